// Round 11
// baseline (220.587 us; speedup 1.0000x reference)
//
#include <hip/hip_runtime.h>
#include <hip/hip_cooperative_groups.h>
#include <cstdint>

namespace cg = cooperative_groups;

// ---------------------------------------------------------------------------
// Round 24. r23 = 215.5us banked (scatter fixed: 98.7 -> <10us). Remaining:
// gemms 2x59 (at the staging-throughput wall) + ~97us front-end/gaps, of
// which ~36-45us is inter-dispatch gaps. Attack: fuse ALL phases into ONE
// persistent cooperative kernel (1024 blocks = 4/CU x 256 CU, the proven
// gemm occupancy) with grid.sync() between phases. gemm tiles pulled from a
// global atomic queue (1 atomic/block/tile) to reproduce the dispatcher's
// dynamic load balance (without it, persistent round-robin piles gemm2's
// 576 tiles onto 144 CUs). gemm math/LDS/swizzle byte-identical to r23.
// Fallback: if hipLaunchCooperativeKernel errors, run the proven r23
// 4-dispatch path (215us, no regression).
// Predict: single mega_k ~160-180us total; conflicts 0; normal WRITE_SIZE.
// WRITE explosion => launch_bounds spill (r19 signature) => revert next.
// ---------------------------------------------------------------------------

#define T_TOK 4096
#define D_DIM 512
#define F_DIM 2048
#define E_EXP 8
#define NROWS 9216      // 8192 assignments + 8*128 pad
#define MAXTILES 72     // NROWS / 128
#define RT_BLKS 64
#define TR_BLKS 4096
#define ZO_BLKS 1024
#define MEGA_BLOCKS 1024
#define G1_TILES (16 * MAXTILES)        // 1152
#define G2_TILES (4 * MAXTILES * 2)     // 576 (splitK2)

typedef __bf16 bf16x8 __attribute__((ext_vector_type(8)));
typedef float  f32x4  __attribute__((ext_vector_type(4)));
typedef unsigned short u16;
typedef unsigned short u16x8 __attribute__((ext_vector_type(8)));

__device__ __forceinline__ u16 f2b(float f) {
    return __builtin_bit_cast(unsigned short, (__bf16)f);
}
__device__ __forceinline__ void gload16(void* lds, const void* g) {
    __builtin_amdgcn_global_load_lds(
        (const __attribute__((address_space(1))) void*)g,
        (__attribute__((address_space(3))) void*)lds, 16, 0, 0);
}
// tanh-approx GELU (err ~3e-4 << bf16 ulp)
__device__ __forceinline__ float gelu_f(float v) {
    float z = 0.7978845608f * (v + 0.044715f * v * v * v);
    float t = 1.0f - 2.0f / (1.0f + __expf(2.0f * z));
    return 0.5f * v * (1.0f + t);
}

// ---------------- shared-memory pool (union across phases) ------------------
struct SmemG { u16 As[128 * 64]; u16 Bs[128 * 64]; };           // 32 KB
struct SmemR { float anl[E_EXP * 544]; int hist[E_EXP]; };      // 17.4 KB
struct SmemS { int soff[E_EXP + 1]; int scnt[E_EXP]; };
union Smem {
    SmemG g;
    float tsh[64][65];
    SmemR r;
    SmemS s;
};

// ---------------- transpose tile body ---------------------------------------
__device__ __forceinline__ void tbody(const float* __restrict__ in,
                                      u16* __restrict__ out, int R, int C,
                                      int c0, int r0, int tid,
                                      float (*t)[65]) {
    int cq = tid & 15, rb = tid >> 4;
#pragma unroll
    for (int pass = 0; pass < 4; ++pass) {
        int rr = rb + pass * 16;
        float4 v = *(const float4*)(in + (size_t)(r0 + rr) * C + c0 + cq * 4);
        t[rr][cq * 4 + 0] = v.x; t[rr][cq * 4 + 1] = v.y;
        t[rr][cq * 4 + 2] = v.z; t[rr][cq * 4 + 3] = v.w;
    }
    __syncthreads();
    int rg = tid & 15, cb = tid >> 4;
#pragma unroll
    for (int pass = 0; pass < 4; ++pass) {
        int c = cb + pass * 16;
        ushort4 o;
        o.x = f2b(t[rg * 4 + 0][c]); o.y = f2b(t[rg * 4 + 1][c]);
        o.z = f2b(t[rg * 4 + 2][c]); o.w = f2b(t[rg * 4 + 3][c]);
        *(ushort4*)(out + (size_t)(c0 + c) * R + r0 + rg * 4) = o;
    }
}

__device__ __forceinline__ void transpose_unit(int tt, int tid, float (*tsh)[65],
                                               const float* W1, u16* W1T,
                                               const float* W2, u16* W2T) {
    if (tt < 2048) {                    // W1 [E][512][2048] -> [E][2048][512]
        int bx = tt & 31, by = (tt >> 5) & 7, bz = tt >> 8;
        size_t zoff = (size_t)bz * D_DIM * F_DIM;
        tbody(W1 + zoff, W1T + zoff, D_DIM, F_DIM, bx * 64, by * 64, tid, tsh);
    } else {                            // W2 [E][2048][512] -> [E][512][2048]
        int t2 = tt - 2048;
        int bx = t2 & 7, by = (t2 >> 3) & 31, bz = t2 >> 8;
        size_t zoff = (size_t)bz * D_DIM * F_DIM;
        tbody(W2 + zoff, W2T + zoff, F_DIM, D_DIM, bx * 64, by * 64, tid, tsh);
    }
}

// ---------------- routing body (one block = 64 tokens) ----------------------
__device__ __forceinline__ void routing_body(
    int b, int tid, float* anl, int* hist,
    const float* __restrict__ x, const float* __restrict__ anchors,
    float* __restrict__ dout_an, float* __restrict__ dout_scores,
    float* __restrict__ dout_idx, int* __restrict__ idxs,
    float* __restrict__ gates, int* __restrict__ cnthist,
    int* __restrict__ ranks) {
    if (tid < E_EXP) hist[tid] = 0;
    for (int i = tid; i < E_EXP * D_DIM; i += 256) {
        int e = i >> 9, d = i & 511;
        anl[e * 544 + (d >> 7) * 136 + (d & 127)] = anchors[i];
    }
    __syncthreads();
    {   // normalize anchors in LDS: 32 threads per anchor
        int e = tid >> 5, l = tid & 31;
        float ss = 0.f;
        for (int d = l; d < D_DIM; d += 32) {
            float v = anl[e * 544 + (d >> 7) * 136 + (d & 127)];
            ss += v * v;
        }
#pragma unroll
        for (int off = 16; off >= 1; off >>= 1) ss += __shfl_xor(ss, off, 32);
        float inv = 1.0f / fmaxf(sqrtf(ss), 1e-8f);
        for (int d = l; d < D_DIM; d += 32) {
            int ix = e * 544 + (d >> 7) * 136 + (d & 127);
            float nv = anl[ix] * inv;
            anl[ix] = nv;
            if (b == 0) dout_an[e * D_DIM + d] = nv;
        }
    }
    __syncthreads();

    int p = tid & 3;
    int tok = b * 64 + (tid >> 2);
    const float4* xr = (const float4*)(x + (size_t)tok * D_DIM + p * 128);
    const float* ab = &anl[p * 136];
    float dot[E_EXP] = {};
    float ss = 0.f;
    for (int c = 0; c < 32; ++c) {
        float4 xv = xr[c];
        ss += xv.x*xv.x + xv.y*xv.y + xv.z*xv.z + xv.w*xv.w;
#pragma unroll
        for (int e = 0; e < E_EXP; ++e) {
            float4 av = *(const float4*)&ab[e * 544 + c * 4];
            dot[e] += xv.x*av.x + xv.y*av.y + xv.z*av.z + xv.w*av.w;
        }
    }
#pragma unroll
    for (int off = 1; off <= 2; off <<= 1) {
        ss += __shfl_xor(ss, off, 64);
#pragma unroll
        for (int e = 0; e < E_EXP; ++e) dot[e] += __shfl_xor(dot[e], off, 64);
    }

    if (p == 0) {
        float inv = 1.0f / fmaxf(sqrtf(ss), 1e-8f);
        float s[E_EXP];
#pragma unroll
        for (int e = 0; e < E_EXP; ++e) s[e] = dot[e] * inv;
        int i0 = 0; float b0 = s[0];
#pragma unroll
        for (int e = 1; e < E_EXP; ++e) if (s[e] > b0) { b0 = s[e]; i0 = e; }
        int i1 = -1; float b1v = -1e30f;
#pragma unroll
        for (int e = 0; e < E_EXP; ++e)
            if (e != i0 && s[e] > b1v) { b1v = s[e]; i1 = e; }
        if (i1 < 0) { i1 = (i0 + 1) & 7; b1v = s[i1]; }   // NaN-safety
        float g0 = 1.0f / (1.0f + expf(b1v - b0));
        float g1 = 1.0f - g0;
#pragma unroll
        for (int e = 0; e < E_EXP; ++e) dout_scores[tok * E_EXP + e] = s[e];
        dout_idx[tok * 2 + 0] = (float)i0;
        dout_idx[tok * 2 + 1] = (float)i1;
        idxs[tok * 2 + 0] = i0; idxs[tok * 2 + 1] = i1;
        gates[tok * 2 + 0] = g0; gates[tok * 2 + 1] = g1;
        int r0 = atomicAdd(&hist[i0], 1);     // LDS atomic: free in-block rank
        int r1 = atomicAdd(&hist[i1], 1);
        ranks[tok * 2 + 0] = r0;
        ranks[tok * 2 + 1] = r1;
    }
    __syncthreads();
    if (tid < E_EXP) cnthist[b * E_EXP + tid] = hist[tid];
}

// ---------------- scatter body (one wave = one assignment) ------------------
__device__ __forceinline__ void scatter_body(
    int p, int lane, const int* soff, const int* __restrict__ cnthist,
    const int* __restrict__ idxs, const int* __restrict__ ranks,
    const float* __restrict__ gates, int* __restrict__ rowmap,
    float* __restrict__ rowgate, u16* __restrict__ Xg,
    const float* __restrict__ x) {
    int t = p >> 1, k = p & 1;
    int e = idxs[t * 2 + k];
    e = min(max(e, 0), E_EXP - 1);
    int rb = t >> 6;                     // routing block of token t
    int v = (lane < rb) ? cnthist[lane * E_EXP + e] : 0;
#pragma unroll
    for (int off = 32; off >= 1; off >>= 1) v += __shfl_xor(v, off, 64);
    int r = soff[e] + v + ranks[t * 2 + k];
    if (lane == 0) {
        rowmap[r] = t;
        rowgate[r] = gates[t * 2 + k];
    }
    const float4* xs = (const float4*)(x + (size_t)t * D_DIM + lane * 8);
    float4 v0 = xs[0], v1 = xs[1];
    u16x8 o = { f2b(v0.x), f2b(v0.y), f2b(v0.z), f2b(v0.w),
                f2b(v1.x), f2b(v1.y), f2b(v1.z), f2b(v1.w) };
    *(u16x8*)(Xg + (size_t)r * D_DIM + lane * 8) = o;
}

// ---------------- grouped GEMM body (r18/r23 proven core) -------------------
// MODE 0: Hg = bf16(gelu(Xg @ W1e^T + b1e))         (N=F, K=D), nT=16
// MODE 1: out[tok] += gate*(Hg @ W2e^T + [z0]b2e)   (N=D, K=F, splitK2), nT=4
// 128x128 tile, 4 waves (2m x 2n, 64x64/wave), 32KB LDS, drain-to-0.
// XOR col swizzle kc^(row&7): global source pre-swizzled, read side XORed.
template <int MODE>
__device__ __forceinline__ void gemm_body(
    int vL, int vTotal, Smem& sm,
    const u16* __restrict__ A, int lda,
    const u16* __restrict__ BtBase, int ldb,
    u16* __restrict__ Hout, const float* __restrict__ b1,
    float* __restrict__ outm, const float* __restrict__ b2,
    const int* __restrict__ rowmap, const float* __restrict__ rowgate,
    const int* __restrict__ offs, int kPer, int nT) {
    int per = vTotal >> 3;
    int tile = (vL & 7) * per + (vL >> 3);   // XCD-ish swizzle (benign)
    int z = 0;
    if (MODE == 1) {                 // split-K 2: high half of tiles is z=1
        int half = vTotal >> 1;
        z = tile >= half; tile -= z * half;
    }
    int mtile = tile / nT;
    int n0 = (tile - mtile * nT) * 128;
    int row0 = mtile * 128;
    if (row0 >= offs[E_EXP]) return;
    int e = 0;
#pragma unroll
    for (int i = 1; i < E_EXP; ++i) if (row0 >= offs[i]) e = i;
    const u16* Bt = BtBase + (size_t)e * D_DIM * F_DIM;
    int k_begin = z * kPer;
    int k_end = k_begin + kPer;

    u16* As = sm.g.As;
    u16* Bs = sm.g.Bs;

    int tid = threadIdx.x;
    int lane = tid & 63;
    int wv = tid >> 6;
    int wm = wv & 1, wn = wv >> 1;
    int kq = lane >> 4;          // quad 0..3
    int l15 = lane & 15;

    const u16* aSrc[4]; const u16* bSrc[4];
    u16* aDst[4]; u16* bDst[4];
#pragma unroll
    for (int i = 0; i < 4; ++i) {
        int slot = i * 256 + tid;
        int m = slot >> 3;
        int kc = slot & 7;
        int kcs = kc ^ (m & 7);
        aSrc[i] = A + (size_t)(row0 + m) * lda + kcs * 8;
        bSrc[i] = Bt + (size_t)(n0 + m) * ldb + kcs * 8;
        aDst[i] = As + slot * 8;
        bDst[i] = Bs + slot * 8;
    }

    f32x4 acc[4][4];
#pragma unroll
    for (int i = 0; i < 4; ++i)
#pragma unroll
        for (int j = 0; j < 4; ++j) acc[i][j] = f32x4{0.f, 0.f, 0.f, 0.f};

    int sx = l15 & 7;            // row&7 == l15&7 (wm*64, i*16 ≡ 0 mod 8)
    for (int k0 = k_begin; k0 < k_end; k0 += 64) {
#pragma unroll
        for (int i = 0; i < 4; ++i) gload16(aDst[i], aSrc[i] + k0);
#pragma unroll
        for (int i = 0; i < 4; ++i) gload16(bDst[i], bSrc[i] + k0);
        asm volatile("s_waitcnt vmcnt(0)" ::: "memory");
        __syncthreads();
#pragma unroll
        for (int kk = 0; kk < 2; ++kk) {
            int kc = kk * 4 + kq;
            int kca = kc ^ sx;   // swizzled column on the read side
            bf16x8 af[4], bfr[4];
#pragma unroll
            for (int i = 0; i < 4; ++i) {
                int rowA = wm * 64 + i * 16 + l15;
                af[i] = *(const bf16x8*)(As + rowA * 64 + kca * 8);
                int rowB = wn * 64 + i * 16 + l15;
                bfr[i] = *(const bf16x8*)(Bs + rowB * 64 + kca * 8);
            }
#pragma unroll
            for (int i = 0; i < 4; ++i)
#pragma unroll
                for (int j = 0; j < 4; ++j)
                    acc[i][j] = __builtin_amdgcn_mfma_f32_16x16x32_bf16(
                        af[i], bfr[j], acc[i][j], 0, 0, 0);
        }
        __syncthreads();
    }

    if constexpr (MODE == 0) {
        const float* b1e = b1 + (size_t)e * F_DIM;
#pragma unroll
        for (int i = 0; i < 4; ++i) {
            int gr = row0 + wm * 64 + i * 16 + kq * 4;
#pragma unroll
            for (int j = 0; j < 4; ++j) {
                int gc = n0 + wn * 64 + j * 16 + l15;
                float bb = b1e[gc];
#pragma unroll
                for (int r = 0; r < 4; ++r) {
                    float v = acc[i][j][r] + bb;
                    Hout[(size_t)(gr + r) * F_DIM + gc] = f2b(gelu_f(v));
                }
            }
        }
    } else {
        const float* b2e = b2 + (size_t)e * D_DIM;
        bool addBias = (k_begin == 0);
#pragma unroll
        for (int i = 0; i < 4; ++i) {
            int grb = row0 + wm * 64 + i * 16 + kq * 4;
#pragma unroll
            for (int r = 0; r < 4; ++r) {
                int tok = rowmap[grb + r];
                float g = rowgate[grb + r];
                if (tok >= 0 && tok < T_TOK) {
                    float* orow = outm + (size_t)tok * D_DIM;
#pragma unroll
                    for (int j = 0; j < 4; ++j) {
                        int gc = n0 + wn * 64 + j * 16 + l15;
                        float bb = addBias ? b2e[gc] : 0.f;
                        atomicAdd(orow + gc, g * (acc[i][j][r] + bb));
                    }
                }
            }
        }
    }
}

// ======================= MEGA persistent cooperative kernel =================
__global__ void __launch_bounds__(256, 4) mega_k(
    const float* __restrict__ x, const float* __restrict__ anchors,
    const float* __restrict__ W1, u16* __restrict__ W1T,
    const float* __restrict__ W2, u16* __restrict__ W2T,
    const float* __restrict__ b1, const float* __restrict__ b2,
    float* __restrict__ outm, float* __restrict__ dout_an,
    float* __restrict__ dout_scores, float* __restrict__ dout_idx,
    int* __restrict__ idxs, float* __restrict__ gates,
    int* __restrict__ cnthist, int* __restrict__ ranks,
    int* __restrict__ rowmap, float* __restrict__ rowgate,
    int* __restrict__ offs, u16* __restrict__ Xg, u16* __restrict__ Hg,
    int* __restrict__ ctr) {
    cg::grid_group grid = cg::this_grid();
    __shared__ __align__(16) Smem sm;
    __shared__ int tgrab;
    int b = blockIdx.x;
    int tid = threadIdx.x;

    // ---- phase A: routing | transposes + zero + init (grid-strided) ----
    if (b < RT_BLKS) {
        routing_body(b, tid, sm.r.anl, sm.r.hist, x, anchors, dout_an,
                     dout_scores, dout_idx, idxs, gates, cnthist, ranks);
    } else {
        for (int u = b - RT_BLKS; u < TR_BLKS + ZO_BLKS + 1;
             u += MEGA_BLOCKS - RT_BLKS) {
            if (u < TR_BLKS) {
                transpose_unit(u, tid, sm.tsh, W1, W1T, W2, W2T);
                __syncthreads();            // LDS reuse across units
            } else if (u < TR_BLKS + ZO_BLKS) {
                int zb = u - TR_BLKS;
                float4* o4 = (float4*)outm;
                int i = zb * 256 + tid;
                o4[i] = float4{0.f, 0.f, 0.f, 0.f};
                o4[i + ZO_BLKS * 256] = float4{0.f, 0.f, 0.f, 0.f};
            } else {
                for (int r = tid; r < NROWS; r += 256) {
                    rowmap[r] = -1; rowgate[r] = 0.f;
                }
                if (tid < 2) ctr[tid] = 0;   // gemm tile queues
            }
        }
    }
    __threadfence();
    grid.sync();

    // ---- phase B: atomic-free scatter (2 assignments per wave) ----
    {
        if (tid < E_EXP) {
            int s = 0;
            for (int bb = 0; bb < RT_BLKS; ++bb) s += cnthist[bb * E_EXP + tid];
            sm.s.scnt[tid] = s;
        }
        __syncthreads();
        if (tid == 0) {
            int acc0 = 0;
            for (int e = 0; e < E_EXP; ++e) {
                sm.s.soff[e] = acc0; acc0 += (sm.s.scnt[e] + 127) & ~127;
            }
            sm.s.soff[E_EXP] = acc0;
        }
        __syncthreads();
        if (b == 0 && tid <= E_EXP) offs[tid] = sm.s.soff[tid];
        int w = tid >> 6, lane = tid & 63;
        int p0 = b * 4 + w;
        scatter_body(p0, lane, sm.s.soff, cnthist, idxs, ranks, gates,
                     rowmap, rowgate, Xg, x);
        scatter_body(p0 + 4096, lane, sm.s.soff, cnthist, idxs, ranks, gates,
                     rowmap, rowgate, Xg, x);
    }
    __threadfence();
    grid.sync();

    // ---- phase C: gemm1, dynamic tile queue ----
    for (;;) {
        if (tid == 0) tgrab = atomicAdd(&ctr[0], 1);
        __syncthreads();
        int t = tgrab;
        __syncthreads();
        if (t >= G1_TILES) break;
        gemm_body<0>(t, G1_TILES, sm, Xg, D_DIM, W1T, D_DIM, Hg, b1,
                     nullptr, nullptr, rowmap, nullptr, offs, D_DIM, 16);
    }
    __threadfence();
    grid.sync();

    // ---- phase D: gemm2, dynamic tile queue ----
    for (;;) {
        if (tid == 0) tgrab = atomicAdd(&ctr[1], 1);
        __syncthreads();
        int t = tgrab;
        __syncthreads();
        if (t >= G2_TILES) break;
        gemm_body<1>(t, G2_TILES, sm, Hg, F_DIM, W2T, F_DIM, nullptr, nullptr,
                     outm, b2, rowmap, rowgate, offs, F_DIM / 2, 4);
    }
}

// ======================= fallback kernels (r23, proven 215us) ===============
#define PRE_BLOCKS (RT_BLKS + TR_BLKS + ZO_BLKS + 1)

__global__ void pre_k(const float* __restrict__ x, const float* __restrict__ anchors,
                      const float* __restrict__ W1, u16* __restrict__ W1T,
                      const float* __restrict__ W2, u16* __restrict__ W2T,
                      float* __restrict__ outm, float* __restrict__ dout_an,
                      float* __restrict__ dout_scores, float* __restrict__ dout_idx,
                      int* __restrict__ idxs, float* __restrict__ gates,
                      int* __restrict__ cnthist, int* __restrict__ ranks,
                      int* __restrict__ rowmap, float* __restrict__ rowgate) {
    __shared__ __align__(16) Smem sm;
    int b = blockIdx.x;
    int tid = threadIdx.x;

    if (b >= RT_BLKS + TR_BLKS + ZO_BLKS) {             // ---- misc init ----
        for (int r = tid; r < NROWS; r += 256) {
            rowmap[r] = -1; rowgate[r] = 0.f;
        }
        return;
    }
    if (b >= RT_BLKS + TR_BLKS) {                       // ---- zero outm ----
        int zb = b - (RT_BLKS + TR_BLKS);
        float4* o4 = (float4*)outm;
        int i = zb * 256 + tid;
        o4[i] = float4{0.f, 0.f, 0.f, 0.f};
        o4[i + ZO_BLKS * 256] = float4{0.f, 0.f, 0.f, 0.f};
        return;
    }
    if (b >= RT_BLKS) {                                 // ---- transposes ----
        transpose_unit(b - RT_BLKS, tid, sm.tsh, W1, W1T, W2, W2T);
        return;
    }
    routing_body(b, tid, sm.r.anl, sm.r.hist, x, anchors, dout_an,
                 dout_scores, dout_idx, idxs, gates, cnthist, ranks);
}

__global__ void scatter_k(const float* __restrict__ x, const int* __restrict__ cnthist,
                          const int* __restrict__ idxs, const int* __restrict__ ranks,
                          const float* __restrict__ gates, int* __restrict__ offs,
                          int* __restrict__ rowmap, float* __restrict__ rowgate,
                          u16* __restrict__ Xg) {
    __shared__ int soff[E_EXP + 1];
    __shared__ int scnt[E_EXP];
    int tid = threadIdx.x;
    if (tid < E_EXP) {
        int s = 0;
        for (int b = 0; b < RT_BLKS; ++b) s += cnthist[b * E_EXP + tid];
        scnt[tid] = s;
    }
    __syncthreads();
    if (tid == 0) {
        int acc = 0;
        for (int e = 0; e < E_EXP; ++e) { soff[e] = acc; acc += (scnt[e] + 127) & ~127; }
        soff[E_EXP] = acc;
    }
    __syncthreads();
    if (blockIdx.x == 0 && tid <= E_EXP) offs[tid] = soff[tid];

    int w = tid >> 6, lane = tid & 63;
    int p = blockIdx.x * 4 + w;          // assignment 0..8191
    scatter_body(p, lane, soff, cnthist, idxs, ranks, gates,
                 rowmap, rowgate, Xg, x);
}

template <int MODE>
__launch_bounds__(256, 4)
__global__ void gemm_k(const u16* __restrict__ A, int lda,
                       const u16* __restrict__ BtBase, int ldb,
                       u16* __restrict__ Hout, const float* __restrict__ b1,
                       float* __restrict__ outm, const float* __restrict__ b2,
                       const int* __restrict__ rowmap, const float* __restrict__ rowgate,
                       const int* __restrict__ offs, int kPer, int nT) {
    __shared__ __align__(16) Smem sm;
    gemm_body<MODE>(blockIdx.x, gridDim.x, sm, A, lda, BtBase, ldb, Hout, b1,
                    outm, b2, rowmap, rowgate, offs, kPer, nT);
}

// ---------------- workspace layout (bytes) ----------------------------------
#define OFF_CNTH    0x10000u     // int[64*8] per-block histograms
#define OFF_OFFS    0x10900u     // int[9]
#define OFF_CTR     0x10A00u     // int[2] gemm tile queues
#define OFF_IDX     0x20000u     // int[T*2]
#define OFF_GATE    0x28000u     // float[T*2]
#define OFF_ROWMAP  0x30000u     // int[NROWS]
#define OFF_ROWGATE 0x40000u     // float[NROWS]
#define OFF_RANK    0x50000u     // int[T*2] within-block ranks
#define OFF_XG      0x900000u    // 9.44 MB u16[NROWS*D]  -> ends 0x1200000
#define OFF_W1T     0x1200000u   // 16.78 MB u16[E][F][D] -> ends 0x2200000
#define OFF_W2T     0x2200000u   // 16.78 MB u16[E][D][F] -> ends 0x3200000
#define OFF_HG      0x3200000u   // 37.75 MB u16[NROWS*F] -> ends 0x5600000

extern "C" void kernel_launch(void* const* d_in, const int* in_sizes, int n_in,
                              void* d_out, int out_size, void* d_ws, size_t ws_size,
                              hipStream_t stream) {
    const float* x       = (const float*)d_in[0];
    const float* anchors = (const float*)d_in[1];
    const float* W1      = (const float*)d_in[2];
    const float* b1      = (const float*)d_in[3];
    const float* W2      = (const float*)d_in[4];
    const float* b2      = (const float*)d_in[5];
    float* out = (float*)d_out;

    char* ws = (char*)d_ws;
    int*   cnthist = (int*)(ws + OFF_CNTH);
    int*   offs    = (int*)(ws + OFF_OFFS);
    int*   ctr     = (int*)(ws + OFF_CTR);
    int*   idxs    = (int*)(ws + OFF_IDX);
    float* gates   = (float*)(ws + OFF_GATE);
    int*   rowmap  = (int*)(ws + OFF_ROWMAP);
    float* rowgate = (float*)(ws + OFF_ROWGATE);
    int*   ranks   = (int*)(ws + OFF_RANK);
    u16*   Xg      = (u16*)(ws + OFF_XG);
    u16*   W1T     = (u16*)(ws + OFF_W1T);
    u16*   W2T     = (u16*)(ws + OFF_W2T);
    u16*   Hg      = (u16*)(ws + OFF_HG);

    // d_out sections (fp32 elements): out | a_n | scores | topk_idx
    float* out_main   = out;
    float* out_an     = out + (size_t)T_TOK * D_DIM;
    float* out_scores = out_an + E_EXP * D_DIM;
    float* out_idx    = out_scores + (size_t)T_TOK * E_EXP;

    // ---- try the persistent cooperative mega-kernel ----
    static int coop = -1;        // -1 unknown, 1 works, 0 failed
    if (coop != 0) {
        void* args[] = {
            (void*)&x, (void*)&anchors, (void*)&W1, (void*)&W1T,
            (void*)&W2, (void*)&W2T, (void*)&b1, (void*)&b2,
            (void*)&out_main, (void*)&out_an, (void*)&out_scores,
            (void*)&out_idx, (void*)&idxs, (void*)&gates, (void*)&cnthist,
            (void*)&ranks, (void*)&rowmap, (void*)&rowgate, (void*)&offs,
            (void*)&Xg, (void*)&Hg, (void*)&ctr };
        hipError_t err = hipLaunchCooperativeKernel(
            (const void*)mega_k, dim3(MEGA_BLOCKS), dim3(256), args, 0, stream);
        if (err == hipSuccess) { coop = 1; return; }
        coop = 0;
        (void)hipGetLastError();   // clear error state, fall through
    }

    // ---- fallback: proven r23 4-dispatch path (215.5us) ----
    pre_k<<<PRE_BLOCKS, 256, 0, stream>>>(x, anchors, W1, W1T, W2, W2T,
                                          out_main, out_an, out_scores, out_idx,
                                          idxs, gates, cnthist, ranks,
                                          rowmap, rowgate);
    scatter_k<<<2048, 256, 0, stream>>>(x, cnthist, idxs, ranks, gates, offs,
                                        rowmap, rowgate, Xg);
    gemm_k<0><<<G1_TILES, 256, 0, stream>>>(
        Xg, D_DIM, W1T, D_DIM, Hg, b1, nullptr, nullptr,
        rowmap, nullptr, offs, D_DIM, 16);
    gemm_k<1><<<G2_TILES, 256, 0, stream>>>(
        Hg, F_DIM, W2T, F_DIM, nullptr, nullptr, out_main, b2,
        rowmap, rowgate, offs, F_DIM / 2, 4);
}